// Round 3
// baseline (1102.319 us; speedup 1.0000x reference)
//
#include <hip/hip_runtime.h>
#include <hip/hip_bf16.h>
#include <math.h>

// ---------------------------------------------------------------------------
// Quantized CNN forward (bitwise-exact vs fp32 reference):
//   block_k: maxpool2( quant_act( conv3x3(x, quant_weight(wk)), ak ) )
//   then global max over HxW, then 1x1 conv (10x128).
// quant_act is monotone => commutes with maxpool (pool raw conv, quantize once).
// CRITICAL: per-output accumulation stays (ci asc, k asc) with FMA — this
// matched the reference bitwise in rounds 1-2 (absmax 0.0). Only tiling changes.
// R3: __launch_bounds__(256) WITHOUT min-waves — R2's (256,4) capped VGPR at 64
// vs ~115 live → scratch spills (WRITE_SIZE 16->69MB, VALUBusy 69->39%).
// ---------------------------------------------------------------------------

__global__ __launch_bounds__(64)
void prep_zero(unsigned* __restrict__ maxb) {
    if (threadIdx.x < 4) maxb[threadIdx.x] = 0u;
}

__global__ __launch_bounds__(256)
void prep_absmax(const float* __restrict__ w1, const float* __restrict__ w2,
                 const float* __restrict__ w3, const float* __restrict__ wc,
                 unsigned* __restrict__ maxb) {
    const float* srcs[4] = {w1, w2, w3, wc};
    const int    ns[4]   = {32*3*9, 64*32*9, 128*64*9, 10*128};
    const int t = blockIdx.y;
    const float* s = srcs[t];
    const int    N = ns[t];
    float m = 0.f;
    for (int i = blockIdx.x * 256 + threadIdx.x; i < N; i += 16 * 256)
        m = fmaxf(m, fabsf(s[i]));
    #pragma unroll
    for (int o = 32; o > 0; o >>= 1) m = fmaxf(m, __shfl_down(m, o));
    __shared__ float red[4];
    const int lane = threadIdx.x & 63, wid = threadIdx.x >> 6;
    if (lane == 0) red[wid] = m;
    __syncthreads();
    if (threadIdx.x == 0) {
        float mm = fmaxf(fmaxf(red[0], red[1]), fmaxf(red[2], red[3]));
        atomicMax(maxb + t, __float_as_uint(mm));  // |w|>=0: uint order == float order
    }
}

__global__ __launch_bounds__(256)
void prep_quant(const float* __restrict__ w1, const float* __restrict__ w2,
                const float* __restrict__ w3, const float* __restrict__ wc,
                const unsigned* __restrict__ maxb,
                float* __restrict__ q1, float* __restrict__ q2,
                float* __restrict__ q3, float* __restrict__ qc) {
    const float* srcs[4] = {w1, w2, w3, wc};
    float*       dsts[4] = {q1, q2, q3, qc};
    const int    ns[4]   = {32*3*9, 64*32*9, 128*64*9, 10*128};
    const int t = blockIdx.y;
    const float* s = srcs[t];
    float*       d = dsts[t];
    const int    N = ns[t];
    const float sc = fmaxf(__uint_as_float(maxb[t]), 1e-8f);  // qmax = 2^(2-1)-1 = 1
    for (int i = blockIdx.x * 256 + threadIdx.x; i < N; i += 16 * 256)
        d[i] = rintf(s[i] / sc) * sc;
}

// Fused conv3x3(pad=1) + maxpool2 + quant_act.
// 16x16 threads; each thread: 2 pooled pixels (x-pair) x 8 output channels.
// Tile covers 32x16 pooled = 64x32 conv pixels; LDS input tile 34x66 (+halo),
// double-buffered, stride 67 for bank spread. Weights load uniform -> s_load.
template<int CIN>
__global__ __launch_bounds__(256)
void conv_act_pool(const float* __restrict__ in, const float* __restrict__ qw,
                   const float* __restrict__ alpha_p, float* __restrict__ out,
                   int Co, int H, int W) {
    const int PH = H >> 1, PW = W >> 1;
    const int tx = threadIdx.x, ty = threadIdx.y;
    const int ngrp = Co >> 3;
    const int b    = blockIdx.z / ngrp;
    const int co0  = (blockIdx.z % ngrp) * 8;
    const int px0  = blockIdx.x * 32 + 2 * tx;   // pooled col pair (px0, px0+1)
    const int py   = blockIdx.y * 16 + ty;       // pooled row
    const int ix0  = blockIdx.x * 64 - 1;        // input col of tile[.][0]
    const int iy0  = blockIdx.y * 32 - 1;        // input row of tile[0][.]

    __shared__ float tile[2][34][67];
    const float* inB = in + (size_t)b * CIN * H * W;

    auto stage = [&](int buf, int ci) {
        const float* inC = inB + (size_t)ci * H * W;
        #pragma unroll
        for (int i = 0; i < 3; ++i) {
            const int r = ty + 16 * i;
            if (r < 34) {
                const int gy = iy0 + r;
                const bool oky = (gy >= 0) && (gy < H);
                #pragma unroll
                for (int j = 0; j < 5; ++j) {
                    const int c = tx + 16 * j;
                    if (c < 66) {
                        const int gx = ix0 + c;
                        float v = 0.f;
                        if (oky && gx >= 0 && gx < W) v = inC[(size_t)gy * W + gx];
                        tile[buf][r][c] = v;
                    }
                }
            }
        }
    };

    float acc[8][8];   // [out-ch][pxpair(2) x prepool(4)]
    #pragma unroll
    for (int c = 0; c < 8; ++c)
        #pragma unroll
        for (int p = 0; p < 8; ++p) acc[c][p] = 0.f;

    stage(0, 0);
    __syncthreads();

    for (int ci = 0; ci < CIN; ++ci) {
        const int buf = ci & 1;
        if (ci + 1 < CIN) stage(buf ^ 1, ci + 1);   // prefetch next channel

        // 4 rows x 6 cols input patch for this thread's 2x(2x2) conv outputs
        float p[4][6];
        #pragma unroll
        for (int r = 0; r < 4; ++r)
            #pragma unroll
            for (int c = 0; c < 6; ++c)
                p[r][c] = tile[buf][2 * ty + r][4 * tx + c];

        #pragma unroll
        for (int c = 0; c < 8; ++c) {
            const float* wp = qw + ((size_t)(co0 + c) * CIN + ci) * 9;  // uniform
            float w[9];
            #pragma unroll
            for (int k = 0; k < 9; ++k) w[k] = wp[k];
            #pragma unroll
            for (int k = 0; k < 9; ++k) {
                const int ky = k / 3, kx = k % 3;
                acc[c][0] += w[k] * p[ky + 0][kx + 0];
                acc[c][1] += w[k] * p[ky + 0][kx + 1];
                acc[c][2] += w[k] * p[ky + 1][kx + 0];
                acc[c][3] += w[k] * p[ky + 1][kx + 1];
                acc[c][4] += w[k] * p[ky + 0][kx + 2];
                acc[c][5] += w[k] * p[ky + 0][kx + 3];
                acc[c][6] += w[k] * p[ky + 1][kx + 2];
                acc[c][7] += w[k] * p[ky + 1][kx + 3];
            }
        }
        __syncthreads();
    }

    if (py < PH && px0 < PW) {   // PW even, px0 even => pair always together
        const float alpha = *alpha_p;
        const float scale = alpha / 3.0f;    // 2^ABITS - 1 = 3
        #pragma unroll
        for (int c = 0; c < 8; ++c) {
            const float m0 = fmaxf(fmaxf(acc[c][0], acc[c][1]),
                                   fmaxf(acc[c][2], acc[c][3]));
            const float m1 = fmaxf(fmaxf(acc[c][4], acc[c][5]),
                                   fmaxf(acc[c][6], acc[c][7]));
            const float y0 = fminf(fmaxf(m0, 0.f), alpha);
            const float y1 = fminf(fmaxf(m1, 0.f), alpha);
            float2 v;
            v.x = rintf(y0 / scale) * scale;
            v.y = rintf(y1 / scale) * scale;
            *(float2*)&out[(((size_t)b * Co + co0 + c) * PH + py) * PW + px0] = v;
        }
    }
}

// One wave per (channel, batch): global max over 28x28.
__global__ __launch_bounds__(64)
void gmax_kernel(const float* __restrict__ h3, float* __restrict__ g) {
    const int c = blockIdx.x, b = blockIdx.y;
    const float* p = h3 + ((size_t)b * 128 + c) * 784;
    float m = -INFINITY;
    for (int i = threadIdx.x; i < 784; i += 64) m = fmaxf(m, p[i]);
    #pragma unroll
    for (int o = 32; o > 0; o >>= 1) m = fmaxf(m, __shfl_down(m, o));
    if (threadIdx.x == 0) g[b * 128 + c] = m;
}

// 1x1 conv 128->10 per batch (same k-ascending FMA order as round 1).
__global__ __launch_bounds__(128)
void classify_kernel(const float* __restrict__ g, const float* __restrict__ qwc,
                     float* __restrict__ out) {
    const int b = blockIdx.x;
    __shared__ float gg[128];
    gg[threadIdx.x] = g[b * 128 + threadIdx.x];
    __syncthreads();
    if (threadIdx.x < 10) {
        float s = 0.f;
        for (int k = 0; k < 128; ++k) s += qwc[threadIdx.x * 128 + k] * gg[k];
        out[b * 10 + threadIdx.x] = s;
    }
}

extern "C" void kernel_launch(void* const* d_in, const int* in_sizes, int n_in,
                              void* d_out, int out_size, void* d_ws, size_t ws_size,
                              hipStream_t stream) {
    const float* x  = (const float*)d_in[0];
    const float* w1 = (const float*)d_in[1];
    const float* w2 = (const float*)d_in[2];
    const float* w3 = (const float*)d_in[3];
    const float* wc = (const float*)d_in[4];
    const float* a1 = (const float*)d_in[5];
    const float* a2 = (const float*)d_in[6];
    const float* a3 = (const float*)d_in[7];

    float* ws = (float*)d_ws;
    size_t o = 0;
    float* qw1 = ws + o; o += 32 * 3 * 9;
    float* qw2 = ws + o; o += 64 * 32 * 9;
    float* qw3 = ws + o; o += 128 * 64 * 9;
    float* qwc = ws + o; o += 10 * 128;
    unsigned* maxb = (unsigned*)(ws + o); o += 4;
    float* g   = ws + o; o += 32 * 128;
    float* h1p = ws + o; o += 32UL * 32 * 112 * 112;
    float* h2p = ws + o; o += 32UL * 64 * 56 * 56;
    float* h3p = ws + o; o += 32UL * 128 * 28 * 28;

    prep_zero<<<1, 64, 0, stream>>>(maxb);
    prep_absmax<<<dim3(16, 4), 256, 0, stream>>>(w1, w2, w3, wc, maxb);
    prep_quant<<<dim3(16, 4), 256, 0, stream>>>(w1, w2, w3, wc, maxb,
                                                qw1, qw2, qw3, qwc);

    // conv1: 3->32, 224x224 -> pooled 112x112. tiles: x=ceil(112/32)=4, y=112/16=7
    conv_act_pool<3><<<dim3(4, 7, 32 * (32 / 8)), dim3(16, 16), 0, stream>>>(
        x, qw1, a1, h1p, 32, 224, 224);
    // conv2: 32->64, pooled 56x56. tiles: x=2, y=4
    conv_act_pool<32><<<dim3(2, 4, 32 * (64 / 8)), dim3(16, 16), 0, stream>>>(
        h1p, qw2, a2, h2p, 64, 112, 112);
    // conv3: 64->128, pooled 28x28. tiles: x=1, y=2
    conv_act_pool<64><<<dim3(1, 2, 32 * (128 / 8)), dim3(16, 16), 0, stream>>>(
        h2p, qw3, a3, h3p, 128, 56, 56);

    gmax_kernel<<<dim3(128, 32), 64, 0, stream>>>(h3p, g);
    classify_kernel<<<32, 128, 0, stream>>>(g, qwc, (float*)d_out);
}

// Round 4
// 852.202 us; speedup vs baseline: 1.2935x; 1.2935x over previous
//
#include <hip/hip_runtime.h>
#include <hip/hip_bf16.h>
#include <math.h>

// ---------------------------------------------------------------------------
// Quantized CNN forward (bitwise-exact vs fp32 reference):
//   block_k: maxpool2( quant_act( conv3x3(x, quant_weight(wk)), ak ) )
//   then global max over HxW, then 1x1 conv (10x128).
// quant_act is monotone => commutes with maxpool (pool raw conv, quantize once).
// CRITICAL: per-output accumulation stays (ci asc, k asc) with FMA — bitwise
// match in rounds 1-3 (absmax 0.0). Only tiling/registers change.
//
// R4: the R1-R3 limiter was ACCUMULATORS SPILLED TO AGPRs (R3: VGPR=80 yet
// occupancy 22% => ~224 unified regs/wave; R1: VGPR=36 with 32 live accs).
// Fix: 1 pooled px/thread x 8ch = 32 accs (~65 live regs total) +
// __launch_bounds__(256,2) so the allocator has slack (cap 256) and never
// resorts to AGPR churn; real occupancy follows actual ~80 VGPR use.
// ---------------------------------------------------------------------------

__global__ __launch_bounds__(64)
void prep_zero(unsigned* __restrict__ maxb) {
    if (threadIdx.x < 4) maxb[threadIdx.x] = 0u;
}

__global__ __launch_bounds__(256)
void prep_absmax(const float* __restrict__ w1, const float* __restrict__ w2,
                 const float* __restrict__ w3, const float* __restrict__ wc,
                 unsigned* __restrict__ maxb) {
    const float* srcs[4] = {w1, w2, w3, wc};
    const int    ns[4]   = {32*3*9, 64*32*9, 128*64*9, 10*128};
    const int t = blockIdx.y;
    const float* s = srcs[t];
    const int    N = ns[t];
    float m = 0.f;
    for (int i = blockIdx.x * 256 + threadIdx.x; i < N; i += 16 * 256)
        m = fmaxf(m, fabsf(s[i]));
    #pragma unroll
    for (int o = 32; o > 0; o >>= 1) m = fmaxf(m, __shfl_down(m, o));
    __shared__ float red[4];
    const int lane = threadIdx.x & 63, wid = threadIdx.x >> 6;
    if (lane == 0) red[wid] = m;
    __syncthreads();
    if (threadIdx.x == 0) {
        float mm = fmaxf(fmaxf(red[0], red[1]), fmaxf(red[2], red[3]));
        atomicMax(maxb + t, __float_as_uint(mm));  // |w|>=0: uint order == float order
    }
}

__global__ __launch_bounds__(256)
void prep_quant(const float* __restrict__ w1, const float* __restrict__ w2,
                const float* __restrict__ w3, const float* __restrict__ wc,
                const unsigned* __restrict__ maxb,
                float* __restrict__ q1, float* __restrict__ q2,
                float* __restrict__ q3, float* __restrict__ qc) {
    const float* srcs[4] = {w1, w2, w3, wc};
    float*       dsts[4] = {q1, q2, q3, qc};
    const int    ns[4]   = {32*3*9, 64*32*9, 128*64*9, 10*128};
    const int t = blockIdx.y;
    const float* s = srcs[t];
    float*       d = dsts[t];
    const int    N = ns[t];
    const float sc = fmaxf(__uint_as_float(maxb[t]), 1e-8f);  // qmax = 2^(2-1)-1 = 1
    for (int i = blockIdx.x * 256 + threadIdx.x; i < N; i += 16 * 256)
        d[i] = rintf(s[i] / sc) * sc;
}

// Fused conv3x3(pad=1) + maxpool2 + quant_act.
// 16x16 threads; each thread: 1 pooled pixel x 8 output channels (32 accs).
// Tile: 16x16 pooled = 32x32 conv px; LDS input tile 34x34 (stride 36:
// rows 16B-aligned, float2 patch reads are 8B-aligned, 2-way banks = free),
// double-buffered. Weights are wave-uniform -> scalar loads, SGPR operands.
template<int CIN>
__global__ __launch_bounds__(256, 2)
void conv_act_pool(const float* __restrict__ in, const float* __restrict__ qw,
                   const float* __restrict__ alpha_p, float* __restrict__ out,
                   int Co, int H, int W) {
    const int PH = H >> 1, PW = W >> 1;
    const int tx = threadIdx.x, ty = threadIdx.y;
    const int ngrp = Co >> 3;
    const int b    = blockIdx.z / ngrp;
    const int co0  = (blockIdx.z % ngrp) * 8;
    const int px   = blockIdx.x * 16 + tx;       // pooled col
    const int py   = blockIdx.y * 16 + ty;       // pooled row
    const int ix0  = blockIdx.x * 32 - 1;        // input col of tile[.][0]
    const int iy0  = blockIdx.y * 32 - 1;        // input row of tile[0][.]

    __shared__ float tile[2][34][36];
    const float* inB = in + (size_t)b * CIN * H * W;

    auto stage = [&](int buf, int ci) {
        const float* inC = inB + (size_t)ci * H * W;
        #pragma unroll
        for (int i = 0; i < 3; ++i) {
            const int r = ty + 16 * i;
            if (r < 34) {
                const int gy = iy0 + r;
                const bool oky = (gy >= 0) && (gy < H);
                #pragma unroll
                for (int j = 0; j < 3; ++j) {
                    const int c = tx + 16 * j;
                    if (c < 34) {
                        const int gx = ix0 + c;
                        float v = 0.f;
                        if (oky && gx >= 0 && gx < W) v = inC[(size_t)gy * W + gx];
                        tile[buf][r][c] = v;
                    }
                }
            }
        }
    };

    float acc[8][4];   // [out-ch][2x2 prepool]
    #pragma unroll
    for (int c = 0; c < 8; ++c)
        #pragma unroll
        for (int p = 0; p < 4; ++p) acc[c][p] = 0.f;

    stage(0, 0);
    __syncthreads();

    for (int ci = 0; ci < CIN; ++ci) {
        const int buf = ci & 1;
        if (ci + 1 < CIN) stage(buf ^ 1, ci + 1);   // prefetch next channel

        // 4x4 patch covering this thread's 2x2 conv outputs; float2 reads
        float p[4][4];
        #pragma unroll
        for (int r = 0; r < 4; ++r) {
            const float2 q0 = *(const float2*)&tile[buf][2 * ty + r][2 * tx];
            const float2 q1 = *(const float2*)&tile[buf][2 * ty + r][2 * tx + 2];
            p[r][0] = q0.x; p[r][1] = q0.y; p[r][2] = q1.x; p[r][3] = q1.y;
        }

        #pragma unroll
        for (int c = 0; c < 8; ++c) {
            const float* wp = qw + ((size_t)(co0 + c) * CIN + ci) * 9;  // uniform
            float w[9];
            #pragma unroll
            for (int k = 0; k < 9; ++k) w[k] = wp[k];
            #pragma unroll
            for (int k = 0; k < 9; ++k) {
                const int ky = k / 3, kx = k % 3;
                acc[c][0] += w[k] * p[ky + 0][kx + 0];
                acc[c][1] += w[k] * p[ky + 0][kx + 1];
                acc[c][2] += w[k] * p[ky + 1][kx + 0];
                acc[c][3] += w[k] * p[ky + 1][kx + 1];
            }
        }
        __syncthreads();
    }

    if (py < PH && px < PW) {
        const float alpha = *alpha_p;
        const float scale = alpha / 3.0f;    // 2^ABITS - 1 = 3
        #pragma unroll
        for (int c = 0; c < 8; ++c) {
            const float m = fmaxf(fmaxf(acc[c][0], acc[c][1]),
                                  fmaxf(acc[c][2], acc[c][3]));
            const float y = fminf(fmaxf(m, 0.f), alpha);
            out[(((size_t)b * Co + co0 + c) * PH + py) * PW + px] =
                rintf(y / scale) * scale;
        }
    }
}

// One wave per (channel, batch): global max over 28x28.
__global__ __launch_bounds__(64)
void gmax_kernel(const float* __restrict__ h3, float* __restrict__ g) {
    const int c = blockIdx.x, b = blockIdx.y;
    const float* p = h3 + ((size_t)b * 128 + c) * 784;
    float m = -INFINITY;
    for (int i = threadIdx.x; i < 784; i += 64) m = fmaxf(m, p[i]);
    #pragma unroll
    for (int o = 32; o > 0; o >>= 1) m = fmaxf(m, __shfl_down(m, o));
    if (threadIdx.x == 0) g[b * 128 + c] = m;
}

// 1x1 conv 128->10 per batch (same k-ascending FMA order as round 1).
__global__ __launch_bounds__(128)
void classify_kernel(const float* __restrict__ g, const float* __restrict__ qwc,
                     float* __restrict__ out) {
    const int b = blockIdx.x;
    __shared__ float gg[128];
    gg[threadIdx.x] = g[b * 128 + threadIdx.x];
    __syncthreads();
    if (threadIdx.x < 10) {
        float s = 0.f;
        for (int k = 0; k < 128; ++k) s += qwc[threadIdx.x * 128 + k] * gg[k];
        out[b * 10 + threadIdx.x] = s;
    }
}

extern "C" void kernel_launch(void* const* d_in, const int* in_sizes, int n_in,
                              void* d_out, int out_size, void* d_ws, size_t ws_size,
                              hipStream_t stream) {
    const float* x  = (const float*)d_in[0];
    const float* w1 = (const float*)d_in[1];
    const float* w2 = (const float*)d_in[2];
    const float* w3 = (const float*)d_in[3];
    const float* wc = (const float*)d_in[4];
    const float* a1 = (const float*)d_in[5];
    const float* a2 = (const float*)d_in[6];
    const float* a3 = (const float*)d_in[7];

    float* ws = (float*)d_ws;
    size_t o = 0;
    float* qw1 = ws + o; o += 32 * 3 * 9;
    float* qw2 = ws + o; o += 64 * 32 * 9;
    float* qw3 = ws + o; o += 128 * 64 * 9;
    float* qwc = ws + o; o += 10 * 128;
    unsigned* maxb = (unsigned*)(ws + o); o += 4;
    float* g   = ws + o; o += 32 * 128;
    float* h1p = ws + o; o += 32UL * 32 * 112 * 112;
    float* h2p = ws + o; o += 32UL * 64 * 56 * 56;
    float* h3p = ws + o; o += 32UL * 128 * 28 * 28;

    prep_zero<<<1, 64, 0, stream>>>(maxb);
    prep_absmax<<<dim3(16, 4), 256, 0, stream>>>(w1, w2, w3, wc, maxb);
    prep_quant<<<dim3(16, 4), 256, 0, stream>>>(w1, w2, w3, wc, maxb,
                                                qw1, qw2, qw3, qwc);

    // conv1: 3->32, 224x224 -> pooled 112x112. tiles: 7x7, z = 32b * 4 grp
    conv_act_pool<3><<<dim3(7, 7, 32 * (32 / 8)), dim3(16, 16), 0, stream>>>(
        x, qw1, a1, h1p, 32, 224, 224);
    // conv2: 32->64, pooled 56x56. tiles: 4x4 (56/16=3.5 -> 4), z = 32b * 8 grp
    conv_act_pool<32><<<dim3(4, 4, 32 * (64 / 8)), dim3(16, 16), 0, stream>>>(
        h1p, qw2, a2, h2p, 64, 112, 112);
    // conv3: 64->128, pooled 28x28. tiles: 2x2, z = 32b * 16 grp
    conv_act_pool<64><<<dim3(2, 2, 32 * (128 / 8)), dim3(16, 16), 0, stream>>>(
        h2p, qw3, a3, h3p, 128, 56, 56);

    gmax_kernel<<<dim3(128, 32), 64, 0, stream>>>(h3p, g);
    classify_kernel<<<32, 128, 0, stream>>>(g, qwc, (float*)d_out);
}

// Round 5
// 691.675 us; speedup vs baseline: 1.5937x; 1.2321x over previous
//
#include <hip/hip_runtime.h>
#include <hip/hip_bf16.h>
#include <math.h>

// ---------------------------------------------------------------------------
// Quantized CNN forward (bitwise-exact vs fp32 reference):
//   block_k: maxpool2( quant_act( conv3x3(x, quant_weight(wk)), ak ) )
//   then global max over HxW, then 1x1 conv (10x128).
// quant_act is monotone => commutes with maxpool (pool raw conv, quantize once).
// CRITICAL: per-output accumulation stays (ci asc, k asc) with FMA — bitwise
// match in rounds 1-4 (absmax 0.0). Only tiling/scheduling changes.
//
// R5: R4 showed VALUBusy 49% / occupancy 41% (=4 waves/SIMD, ~128 unified
// regs/wave: AGPR overflow) and a per-ci vmcnt stall: staging loads issued
// immediately before the ds_writes that need them -> full memory latency
// exposed every iteration. Fix: (a) depth-2 register pipeline — loads for
// ci+2 issued before compute(ci), consumed by ds_write at ci+1 (latency
// hidden under a full FMA phase); (b) __launch_bounds__(256,5) caps unified
// regs at 102 (live ~85 fits; no AGPRs, 5 waves/SIMD); (c) unroll 2 to stay
// inside the 32KB I$.
// ---------------------------------------------------------------------------

__global__ __launch_bounds__(64)
void prep_zero(unsigned* __restrict__ maxb) {
    if (threadIdx.x < 4) maxb[threadIdx.x] = 0u;
}

__global__ __launch_bounds__(256)
void prep_absmax(const float* __restrict__ w1, const float* __restrict__ w2,
                 const float* __restrict__ w3, const float* __restrict__ wc,
                 unsigned* __restrict__ maxb) {
    const float* srcs[4] = {w1, w2, w3, wc};
    const int    ns[4]   = {32*3*9, 64*32*9, 128*64*9, 10*128};
    const int t = blockIdx.y;
    const float* s = srcs[t];
    const int    N = ns[t];
    float m = 0.f;
    for (int i = blockIdx.x * 256 + threadIdx.x; i < N; i += 16 * 256)
        m = fmaxf(m, fabsf(s[i]));
    #pragma unroll
    for (int o = 32; o > 0; o >>= 1) m = fmaxf(m, __shfl_down(m, o));
    __shared__ float red[4];
    const int lane = threadIdx.x & 63, wid = threadIdx.x >> 6;
    if (lane == 0) red[wid] = m;
    __syncthreads();
    if (threadIdx.x == 0) {
        float mm = fmaxf(fmaxf(red[0], red[1]), fmaxf(red[2], red[3]));
        atomicMax(maxb + t, __float_as_uint(mm));  // |w|>=0: uint order == float order
    }
}

__global__ __launch_bounds__(256)
void prep_quant(const float* __restrict__ w1, const float* __restrict__ w2,
                const float* __restrict__ w3, const float* __restrict__ wc,
                const unsigned* __restrict__ maxb,
                float* __restrict__ q1, float* __restrict__ q2,
                float* __restrict__ q3, float* __restrict__ qc) {
    const float* srcs[4] = {w1, w2, w3, wc};
    float*       dsts[4] = {q1, q2, q3, qc};
    const int    ns[4]   = {32*3*9, 64*32*9, 128*64*9, 10*128};
    const int t = blockIdx.y;
    const float* s = srcs[t];
    float*       d = dsts[t];
    const int    N = ns[t];
    const float sc = fmaxf(__uint_as_float(maxb[t]), 1e-8f);  // qmax = 2^(2-1)-1 = 1
    for (int i = blockIdx.x * 256 + threadIdx.x; i < N; i += 16 * 256)
        d[i] = rintf(s[i] / sc) * sc;
}

// Fused conv3x3(pad=1) + maxpool2 + quant_act.
// 16x16 threads; each thread: 1 pooled pixel x 8 output channels (32 accs).
// Tile: 16x16 pooled = 32x32 conv px; LDS 34x34 tile (stride 36), 2 buffers.
// Staging is software-pipelined through registers (depth 2).
template<int CIN>
__global__ __launch_bounds__(256, 5)
void conv_act_pool(const float* __restrict__ in, const float* __restrict__ qw,
                   const float* __restrict__ alpha_p, float* __restrict__ out,
                   int Co, int H, int W) {
    const int PH = H >> 1, PW = W >> 1;
    const int tx = threadIdx.x, ty = threadIdx.y;
    const int ngrp = Co >> 3;
    const int b    = blockIdx.z / ngrp;
    const int co0  = (blockIdx.z % ngrp) * 8;
    const int px   = blockIdx.x * 16 + tx;       // pooled col
    const int py   = blockIdx.y * 16 + ty;       // pooled row
    const int ix0  = blockIdx.x * 32 - 1;        // input col of tile[.][0]
    const int iy0  = blockIdx.y * 32 - 1;        // input row of tile[0][.]

    __shared__ float tile[2][34][36];
    const float* inB = in + (size_t)b * CIN * H * W;

    // Per-thread staging slots, hoisted: index + validity computed ONCE.
    int  sidx[3][3];
    bool sok [3][3];
    #pragma unroll
    for (int i = 0; i < 3; ++i)
        #pragma unroll
        for (int j = 0; j < 3; ++j) {
            const int r = ty + 16 * i, c = tx + 16 * j;
            const int gy = iy0 + r, gx = ix0 + c;
            const bool inimg = (r < 34) && (c < 34) &&
                               (gy >= 0) && (gy < H) && (gx >= 0) && (gx < W);
            sok[i][j]  = inimg;
            sidx[i][j] = inimg ? (gy * W + gx) : 0;
        }

    float v[3][3];   // in-flight staged values (register pipeline)
    auto load_regs = [&](int ci) {
        const float* inC = inB + (size_t)ci * H * W;
        #pragma unroll
        for (int i = 0; i < 3; ++i)
            #pragma unroll
            for (int j = 0; j < 3; ++j)
                v[i][j] = sok[i][j] ? inC[sidx[i][j]] : 0.f;
    };
    auto store_tile = [&](int buf) {
        #pragma unroll
        for (int i = 0; i < 3; ++i)
            #pragma unroll
            for (int j = 0; j < 3; ++j) {
                const int r = ty + 16 * i, c = tx + 16 * j;
                if (r < 34 && c < 34) tile[buf][r][c] = v[i][j];
            }
    };

    float acc[8][4];   // [out-ch][2x2 prepool]
    #pragma unroll
    for (int c = 0; c < 8; ++c)
        #pragma unroll
        for (int p = 0; p < 4; ++p) acc[c][p] = 0.f;

    // Pipeline prologue: buf0 <- ch0; regs <- ch1.
    load_regs(0);
    store_tile(0);
    if (CIN > 1) load_regs(1);
    __syncthreads();

    #pragma unroll 2
    for (int ci = 0; ci < CIN; ++ci) {
        const int buf = ci & 1;
        if (ci + 1 < CIN) {
            store_tile(buf ^ 1);                 // v holds ci+1 (loads aged ~1 iter)
            if (ci + 2 < CIN) load_regs(ci + 2); // issue next loads early
        }

        // 4x4 patch covering this thread's 2x2 conv outputs; float2 reads
        float p[4][4];
        #pragma unroll
        for (int r = 0; r < 4; ++r) {
            const float2 q0 = *(const float2*)&tile[buf][2 * ty + r][2 * tx];
            const float2 q1 = *(const float2*)&tile[buf][2 * ty + r][2 * tx + 2];
            p[r][0] = q0.x; p[r][1] = q0.y; p[r][2] = q1.x; p[r][3] = q1.y;
        }

        #pragma unroll
        for (int c = 0; c < 8; ++c) {
            const float* wp = qw + ((size_t)(co0 + c) * CIN + ci) * 9;  // uniform
            float w[9];
            #pragma unroll
            for (int k = 0; k < 9; ++k) w[k] = wp[k];
            #pragma unroll
            for (int k = 0; k < 9; ++k) {
                const int ky = k / 3, kx = k % 3;
                acc[c][0] += w[k] * p[ky + 0][kx + 0];
                acc[c][1] += w[k] * p[ky + 0][kx + 1];
                acc[c][2] += w[k] * p[ky + 1][kx + 0];
                acc[c][3] += w[k] * p[ky + 1][kx + 1];
            }
        }
        __syncthreads();
    }

    if (py < PH && px < PW) {
        const float alpha = *alpha_p;
        const float scale = alpha / 3.0f;    // 2^ABITS - 1 = 3
        #pragma unroll
        for (int c = 0; c < 8; ++c) {
            const float m = fmaxf(fmaxf(acc[c][0], acc[c][1]),
                                  fmaxf(acc[c][2], acc[c][3]));
            const float y = fminf(fmaxf(m, 0.f), alpha);
            out[(((size_t)b * Co + co0 + c) * PH + py) * PW + px] =
                rintf(y / scale) * scale;
        }
    }
}

// One wave per (channel, batch): global max over 28x28.
__global__ __launch_bounds__(64)
void gmax_kernel(const float* __restrict__ h3, float* __restrict__ g) {
    const int c = blockIdx.x, b = blockIdx.y;
    const float* p = h3 + ((size_t)b * 128 + c) * 784;
    float m = -INFINITY;
    for (int i = threadIdx.x; i < 784; i += 64) m = fmaxf(m, p[i]);
    #pragma unroll
    for (int o = 32; o > 0; o >>= 1) m = fmaxf(m, __shfl_down(m, o));
    if (threadIdx.x == 0) g[b * 128 + c] = m;
}

// 1x1 conv 128->10 per batch (same k-ascending FMA order as round 1).
__global__ __launch_bounds__(128)
void classify_kernel(const float* __restrict__ g, const float* __restrict__ qwc,
                     float* __restrict__ out) {
    const int b = blockIdx.x;
    __shared__ float gg[128];
    gg[threadIdx.x] = g[b * 128 + threadIdx.x];
    __syncthreads();
    if (threadIdx.x < 10) {
        float s = 0.f;
        for (int k = 0; k < 128; ++k) s += qwc[threadIdx.x * 128 + k] * gg[k];
        out[b * 10 + threadIdx.x] = s;
    }
}

extern "C" void kernel_launch(void* const* d_in, const int* in_sizes, int n_in,
                              void* d_out, int out_size, void* d_ws, size_t ws_size,
                              hipStream_t stream) {
    const float* x  = (const float*)d_in[0];
    const float* w1 = (const float*)d_in[1];
    const float* w2 = (const float*)d_in[2];
    const float* w3 = (const float*)d_in[3];
    const float* wc = (const float*)d_in[4];
    const float* a1 = (const float*)d_in[5];
    const float* a2 = (const float*)d_in[6];
    const float* a3 = (const float*)d_in[7];

    float* ws = (float*)d_ws;
    size_t o = 0;
    float* qw1 = ws + o; o += 32 * 3 * 9;
    float* qw2 = ws + o; o += 64 * 32 * 9;
    float* qw3 = ws + o; o += 128 * 64 * 9;
    float* qwc = ws + o; o += 10 * 128;
    unsigned* maxb = (unsigned*)(ws + o); o += 4;
    float* g   = ws + o; o += 32 * 128;
    float* h1p = ws + o; o += 32UL * 32 * 112 * 112;
    float* h2p = ws + o; o += 32UL * 64 * 56 * 56;
    float* h3p = ws + o; o += 32UL * 128 * 28 * 28;

    prep_zero<<<1, 64, 0, stream>>>(maxb);
    prep_absmax<<<dim3(16, 4), 256, 0, stream>>>(w1, w2, w3, wc, maxb);
    prep_quant<<<dim3(16, 4), 256, 0, stream>>>(w1, w2, w3, wc, maxb,
                                                qw1, qw2, qw3, qwc);

    // conv1: 3->32, 224x224 -> pooled 112x112. tiles: 7x7, z = 32b * 4 grp
    conv_act_pool<3><<<dim3(7, 7, 32 * (32 / 8)), dim3(16, 16), 0, stream>>>(
        x, qw1, a1, h1p, 32, 224, 224);
    // conv2: 32->64, pooled 56x56. tiles: 4x4, z = 32b * 8 grp
    conv_act_pool<32><<<dim3(4, 4, 32 * (64 / 8)), dim3(16, 16), 0, stream>>>(
        h1p, qw2, a2, h2p, 64, 112, 112);
    // conv3: 64->128, pooled 28x28. tiles: 2x2, z = 32b * 16 grp
    conv_act_pool<64><<<dim3(2, 2, 32 * (128 / 8)), dim3(16, 16), 0, stream>>>(
        h2p, qw3, a3, h3p, 128, 56, 56);

    gmax_kernel<<<dim3(128, 32), 64, 0, stream>>>(h3p, g);
    classify_kernel<<<32, 128, 0, stream>>>(g, qwc, (float*)d_out);
}